// Round 5
// baseline (1576.054 us; speedup 1.0000x reference)
//
#include <hip/hip_runtime.h>

// MHSA with relative position bias (Swin window attention), MI355X gfx950.
// B=2048 windows, N=49 tokens, C=1024, 16 heads x 64. fp16 MFMA, fp32 accum.
// Round 5: R4 pipeline kept verbatim; LDS panel re-layout so every MFMA
// k-step fragment read is a CONTIGUOUS 1KB block with R2's measured-zero-
// conflict lane->chunk permutation:
//   slot(16KB) = [2 ksteps][8 rowblocks][1KB], block = 32 rows x 16 cols,
//   data(r,h) at chunk sigma = 4*(r&15) + ((2h + (r>>4)) ^ ((r>>1)&3)).
// Staging writes linear dest; sigma^-1 folded into the global source addr.

typedef _Float16 f16;
typedef _Float16 f16x8 __attribute__((ext_vector_type(8)));
typedef _Float16 f16x4 __attribute__((ext_vector_type(4)));
typedef float f32x4 __attribute__((ext_vector_type(4)));
typedef float f32x16 __attribute__((ext_vector_type(16)));

#define G1P(p) ((const __attribute__((address_space(1))) unsigned int*)(p))
#define L3P(p) ((__attribute__((address_space(3))) unsigned int*)(p))

static const size_t MROW_MAX = 100351;   // clamp for padded rows 49..63 (attn)

// ---------------- fp32 -> fp16 convert (vec4) ----------------
__global__ void cvt_kernel(const float* __restrict__ in, f16* __restrict__ out, int n4) {
  int i = blockIdx.x * blockDim.x + threadIdx.x;
  int stride = gridDim.x * blockDim.x;
  const float4* in4 = (const float4*)in;
  f16x4* out4 = (f16x4*)out;
  for (; i < n4; i += stride) {
    float4 v = in4[i];
    f16x4 o = { (f16)v.x, (f16)v.y, (f16)v.z, (f16)v.w };
    out4[i] = o;
  }
}

// ---------------- bias table: bias_all[h][64][64], mask folded in ----------------
__global__ void bias_kernel(const float* __restrict__ rpb, float* __restrict__ bias_all) {
  int h = blockIdx.x;
  for (int e = threadIdx.x; e < 4096; e += blockDim.x) {
    int n = e >> 6, m = e & 63;
    float v = -1e30f;
    if (n < 49 && m < 49) {
      int in_ = n / 7, jn = n % 7, im = m / 7, jm = m % 7;
      v = rpb[h * 169 + (im - in_ + 6) * 13 + (jm - jn + 6)];
    }
    bias_all[h * 4096 + e] = v;
  }
}

// ---------------- 256x256 pipelined GEMM: C[M,N] = A[M,K=1024] @ B[N,K]^T + bias ----
#define WVM(N) asm volatile("s_waitcnt vmcnt(" #N ")" ::: "memory")
#define WLG    asm volatile("s_waitcnt lgkmcnt(0)" ::: "memory")
#define SB     __builtin_amdgcn_s_barrier()
#define SCB    __builtin_amdgcn_sched_barrier(0)
#define MF(a, b, c) __builtin_amdgcn_mfma_f32_32x32x16_f16(a, b, c, 0, 0, 0)

// stage one K-half pair (A 16KB + B 16KB); per wave 2 dest KB-blocks each.
// dest block bi = wid*2+s  ->  (kstep q = bi>>3, rowblock rb = bi&7);
// lane l supplies data (r = (u&1)*16 + (l>>2), h = u>>1), u = (l&3)^((l>>3)&3).
#define STG(CE, SLOT)                                                                       \
  {                                                                                         \
    const f16* ga_ = Ap + arow_g + (CE) + scol;                                             \
    __builtin_amdgcn_global_load_lds(G1P(ga_), L3P(lds + (SLOT) * 16384 + wid * 2048), 16, 0, 0); \
    __builtin_amdgcn_global_load_lds(G1P(ga_ + 32 * 1024), L3P(lds + (SLOT) * 16384 + wid * 2048 + 1024), 16, 0, 0); \
    const f16* gb_ = Bp + brow_g + (CE) + scol;                                             \
    __builtin_amdgcn_global_load_lds(G1P(gb_), L3P(lds + 65536 + (SLOT) * 16384 + wid * 2048), 16, 0, 0); \
    __builtin_amdgcn_global_load_lds(G1P(gb_ + 32 * 1024), L3P(lds + 65536 + (SLOT) * 16384 + wid * 2048 + 1024), 16, 0, 0); \
  }

// frag reads: contiguous 1KB per read. A block (q, wm*4+rg); B block (q, wn*2+cg).
#define READS(AF, BF, RSLOT)                                                                \
  {                                                                                         \
    const char* ab_ = lds + (RSLOT) * 16384 + arb;                                          \
    AF[0] = *(const f16x8*)(ab_ + 0 * 1024);        AF[1] = *(const f16x8*)(ab_ + 8192 + 0 * 1024); \
    AF[2] = *(const f16x8*)(ab_ + 1 * 1024);        AF[3] = *(const f16x8*)(ab_ + 8192 + 1 * 1024); \
    AF[4] = *(const f16x8*)(ab_ + 2 * 1024);        AF[5] = *(const f16x8*)(ab_ + 8192 + 2 * 1024); \
    AF[6] = *(const f16x8*)(ab_ + 3 * 1024);        AF[7] = *(const f16x8*)(ab_ + 8192 + 3 * 1024); \
    const char* bb_ = lds + 65536 + (RSLOT) * 16384 + brb;                                  \
    BF[0] = *(const f16x8*)(bb_ + 0 * 1024);        BF[1] = *(const f16x8*)(bb_ + 8192 + 0 * 1024); \
    BF[2] = *(const f16x8*)(bb_ + 1 * 1024);        BF[3] = *(const f16x8*)(bb_ + 8192 + 1 * 1024); \
  }

// 16 MFMAs: kstep0 cluster then kstep1 (acc dep distance 8)
#define MFMAS(AF, BF)                                                                       \
  __builtin_amdgcn_s_setprio(1);                                                            \
  acc[0][0] = MF(AF[0], BF[0], acc[0][0]); acc[1][0] = MF(AF[2], BF[0], acc[1][0]);         \
  acc[2][0] = MF(AF[4], BF[0], acc[2][0]); acc[3][0] = MF(AF[6], BF[0], acc[3][0]);         \
  acc[0][1] = MF(AF[0], BF[2], acc[0][1]); acc[1][1] = MF(AF[2], BF[2], acc[1][1]);         \
  acc[2][1] = MF(AF[4], BF[2], acc[2][1]); acc[3][1] = MF(AF[6], BF[2], acc[3][1]);         \
  acc[0][0] = MF(AF[1], BF[1], acc[0][0]); acc[1][0] = MF(AF[3], BF[1], acc[1][0]);         \
  acc[2][0] = MF(AF[5], BF[1], acc[2][0]); acc[3][0] = MF(AF[7], BF[1], acc[3][0]);         \
  acc[0][1] = MF(AF[1], BF[3], acc[0][1]); acc[1][1] = MF(AF[3], BF[3], acc[1][1]);         \
  acc[2][1] = MF(AF[5], BF[3], acc[2][1]); acc[3][1] = MF(AF[7], BF[3], acc[3][1]);         \
  __builtin_amdgcn_s_setprio(0);

template <typename OutT>
__global__ __launch_bounds__(512, 2)
void gemm256(const f16* __restrict__ Ap, const f16* __restrict__ Bp,
             const float* __restrict__ bias, OutT* __restrict__ C,
             int N, int ntiles_n) {
  __shared__ char lds[131072];  // A slots 0..3 at 0; B slots 0..3 at 65536
  const int tid = threadIdx.x;
  const int wid = tid >> 6, ln = tid & 63;
  const int l31 = ln & 31, l5 = ln >> 5;
  const int wm = wid >> 2, wn = wid & 3;

  // read-side lane constant: chunk byte offset within a 1KB k-step block
  //   sigma(r=l31, h=l5) = 4*(r&15) + ((2h + (r>>4)) ^ ((r>>1)&3)
  const int chb = (4 * (l31 & 15) + ((2 * l5 + (l31 >> 4)) ^ ((l31 >> 1) & 3))) << 4;
  const int arb = wm * 4096 + chb;   // A: rowblock base (wm*4 blocks) + chunk
  const int brb = wn * 2048 + chb;   // B: rowblock base (wn*2 blocks) + chunk

  // staging-side lane constants: sigma^-1 for linear dest (dest chunk = lane)
  const int su = (ln & 3) ^ ((ln >> 3) & 3);
  const int ssr = (su & 1) * 16 + (ln >> 2);          // source row within 32-block
  const int scol = (wid >> 2) * 16 + (su >> 1) * 8;   // kstep sel + 16B half sel

  // XCD-chunked 1D swizzle (grid divisible by 8), n-fastest for A-panel L2 reuse
  const int nblk = gridDim.x;
  const int wg = (blockIdx.x & 7) * (nblk >> 3) + (blockIdx.x >> 3);
  const int bn = wg % ntiles_n, bm = wg / ntiles_n;
  const int m0 = bm * 256, n0 = bn * 256;

  const size_t arow_g = (size_t)(m0 + (wid & 3) * 64 + ssr) * 1024;
  const size_t brow_g = (size_t)(n0 + (wid & 3) * 64 + ssr) * 1024;

  f32x16 acc[4][2];
#pragma unroll
  for (int i = 0; i < 4; ++i)
#pragma unroll
    for (int j = 0; j < 2; ++j)
      acc[i][j] = (f32x16){0.f, 0.f, 0.f, 0.f, 0.f, 0.f, 0.f, 0.f,
                           0.f, 0.f, 0.f, 0.f, 0.f, 0.f, 0.f, 0.f};
  f16x8 af0[8], af1[8], bf0[4], bf1[4];

  // prologue: stage halves 0..3 into slots 0..3; read frags of half 0
  STG(0, 0); STG(32, 1); STG(64, 2); STG(96, 3);
  WVM(8);            // halves 0,1 landed
  SB; SCB;
  READS(af0, bf0, 0);
  WLG;               // frags0 ready (and read complete before staging slot 0 again)
  SB; SCB;

  // main loop: phases 0..27 (compute half p; read half p+1; stage half p+4)
  int ce = 128;      // element column of next staged half
  for (int i = 0; i < 7; ++i) {
    READS(af1, bf1, 1); STG(ce, 0);       SCB; MFMAS(af0, bf0); WLG; WVM(8); SB; SCB;
    READS(af0, bf0, 2); STG(ce + 32, 1);  SCB; MFMAS(af1, bf1); WLG; WVM(8); SB; SCB;
    READS(af1, bf1, 3); STG(ce + 64, 2);  SCB; MFMAS(af0, bf0); WLG; WVM(8); SB; SCB;
    READS(af0, bf0, 0); STG(ce + 96, 3);  SCB; MFMAS(af1, bf1); WLG; WVM(8); SB; SCB;
    ce += 128;
  }
  // drain: phases 28..31
  READS(af1, bf1, 1); SCB; MFMAS(af0, bf0); WLG; WVM(4); SB; SCB;
  READS(af0, bf0, 2); SCB; MFMAS(af1, bf1); WLG; WVM(0); SB; SCB;
  READS(af1, bf1, 3); SCB; MFMAS(af0, bf0); WLG; SB; SCB;
  MFMAS(af1, bf1);

  // epilogue: C row = rg*32 + (r&3) + 8*(r>>2) + 4*l5, col = cg*32 + l31
  float bv[2];
#pragma unroll
  for (int j = 0; j < 2; ++j) bv[j] = bias[n0 + wn * 64 + j * 32 + l31];
#pragma unroll
  for (int rg = 0; rg < 4; ++rg)
#pragma unroll
    for (int cg = 0; cg < 2; ++cg)
#pragma unroll
      for (int r = 0; r < 16; ++r) {
        int grow = m0 + wm * 128 + rg * 32 + (r & 3) + 8 * (r >> 2) + 4 * l5;
        int gcol = n0 + wn * 64 + cg * 32 + l31;
        C[(size_t)grow * N + gcol] = (OutT)(acc[rg][cg][r] + bv[cg]);
      }
}

// ---------------- attention: one wave per (window, head) ----------------
__global__ __launch_bounds__(64)
void attn_kernel(const f16* __restrict__ qkv,        // [MTOT][3072] q|k|v
                 const float* __restrict__ bias_all, // [16][64][64]
                 f16* __restrict__ out) {             // [MTOT][1024]
  __shared__ char lds[24576];  // K:[0,8K)  Vt:[8K,16K)  P:[16K,24K)
  const int bh = blockIdx.x;
  const int b = bh >> 4, h = bh & 15;
  const int ln = threadIdx.x;
  const int l15 = ln & 15, lhi = ln >> 4;
  const size_t base = (size_t)b * 49;

  f16x8 qf[4][2];
#pragma unroll
  for (int t = 0; t < 4; ++t) {
    size_t row = base + t * 16 + l15;
    if (row > MROW_MAX) row = MROW_MAX;
    const f16* qp = qkv + row * 3072 + h * 64 + lhi * 8;
    qf[t][0] = *(const f16x8*)(qp);
    qf[t][1] = *(const f16x8*)(qp + 32);
  }
  {
    int rA = ln >> 3, lc = ln & 7;
#pragma unroll
    for (int c = 0; c < 8; ++c) {
      int r = c * 8 + rA;
      int ce = (lc ^ (r & 7)) << 3;
      size_t row = base + r;
      if (row > MROW_MAX) row = MROW_MAX;
      const f16* g = qkv + row * 3072 + 1024 + h * 64 + ce;
      __builtin_amdgcn_global_load_lds(G1P(g), L3P(lds + c * 1024), 16, 0, 0);
    }
  }
  {
    size_t row = base + ln;
    if (row > MROW_MAX) row = MROW_MAX;
    const f16* vp = qkv + row * 3072 + 2048 + h * 64;
    f16x8 vr[8];
#pragma unroll
    for (int j = 0; j < 8; ++j) vr[j] = *(const f16x8*)(vp + j * 8);
#pragma unroll
    for (int d = 0; d < 64; ++d)
      *(f16*)(lds + 8192 + d * 128 + ((ln * 2) ^ ((d & 7) << 4))) = vr[d >> 3][d & 7];
  }
  __syncthreads();

  f32x4 acc[4][4];
#pragma unroll
  for (int i = 0; i < 4; ++i)
#pragma unroll
    for (int j = 0; j < 4; ++j) acc[i][j] = (f32x4){0.f, 0.f, 0.f, 0.f};
#pragma unroll
  for (int kk = 0; kk < 2; ++kk) {
    f16x8 bf[4];
#pragma unroll
    for (int t = 0; t < 4; ++t) {
      int mr = t * 16 + l15;
      int pb = (kk * 64 + lhi * 16) ^ ((mr & 7) << 4);
      bf[t] = *(const f16x8*)(lds + mr * 128 + pb);
    }
#pragma unroll
    for (int i = 0; i < 4; ++i)
#pragma unroll
      for (int j = 0; j < 4; ++j)
        acc[i][j] = __builtin_amdgcn_mfma_f32_16x16x32_f16(qf[i][kk], bf[j], acc[i][j], 0, 0, 0);
  }

  const float* bb = bias_all + h * 4096;
#pragma unroll
  for (int i = 0; i < 4; ++i) {
#pragma unroll
    for (int r = 0; r < 4; ++r) {
      int n = i * 16 + lhi * 4 + r;
      float lv[4];
#pragma unroll
      for (int j = 0; j < 4; ++j)
        lv[j] = acc[i][j][r] * 0.125f + bb[n * 64 + j * 16 + l15];
      float Mx = fmaxf(fmaxf(lv[0], lv[1]), fmaxf(lv[2], lv[3]));
#pragma unroll
      for (int off = 1; off < 16; off <<= 1) Mx = fmaxf(Mx, __shfl_xor(Mx, off));
      float s = 0.f;
#pragma unroll
      for (int j = 0; j < 4; ++j) { lv[j] = __expf(lv[j] - Mx); s += lv[j]; }
#pragma unroll
      for (int off = 1; off < 16; off <<= 1) s += __shfl_xor(s, off);
      float inv = 1.f / s;
#pragma unroll
      for (int j = 0; j < 4; ++j) {
        int m = j * 16 + l15;
        *(f16*)(lds + 16384 + n * 128 + ((m * 2) ^ ((n & 7) << 4))) = (f16)(lv[j] * inv);
      }
    }
  }
  __syncthreads();

  f32x4 o[4][4];
#pragma unroll
  for (int i = 0; i < 4; ++i)
#pragma unroll
    for (int j = 0; j < 4; ++j) o[i][j] = (f32x4){0.f, 0.f, 0.f, 0.f};
#pragma unroll
  for (int kk = 0; kk < 2; ++kk) {
    f16x8 af[4], bf[4];
#pragma unroll
    for (int t = 0; t < 4; ++t) {
      int nr = t * 16 + l15;
      int pb = (kk * 64 + lhi * 16) ^ ((nr & 7) << 4);
      af[t] = *(const f16x8*)(lds + 16384 + nr * 128 + pb);
      bf[t] = *(const f16x8*)(lds + 8192 + nr * 128 + pb);
    }
#pragma unroll
    for (int i = 0; i < 4; ++i)
#pragma unroll
      for (int j = 0; j < 4; ++j)
        o[i][j] = __builtin_amdgcn_mfma_f32_16x16x32_f16(af[i], bf[j], o[i][j], 0, 0, 0);
  }
#pragma unroll
  for (int i = 0; i < 4; ++i)
#pragma unroll
    for (int j = 0; j < 4; ++j)
#pragma unroll
      for (int r = 0; r < 4; ++r) {
        int n = i * 16 + lhi * 4 + r;
        if (n < 49)
          out[(base + n) * 1024 + h * 64 + j * 16 + l15] = (f16)o[i][j][r];
      }
}

extern "C" void kernel_launch(void* const* d_in, const int* in_sizes, int n_in,
                              void* d_out, int out_size, void* d_ws, size_t ws_size,
                              hipStream_t stream) {
  const float* x      = (const float*)d_in[0];  // [100352][1024]
  const float* qkv_w  = (const float*)d_in[1];  // [3072][1024]
  const float* qkv_b  = (const float*)d_in[2];  // [3072]
  const float* rpb    = (const float*)d_in[3];  // [16][13][13]
  const float* proj_w = (const float*)d_in[4];  // [1024][1024]
  const float* proj_b = (const float*)d_in[5];  // [1024]
  float* out = (float*)d_out;

  char* ws = (char*)d_ws;
  f16*   x16      = (f16*)(ws);                              // 205,520,896
  f16*   wq16     = (f16*)(ws + 205520896);                  //   6,291,456
  f16*   wp16     = (f16*)(ws + 211812352);                  //   2,097,152
  f16*   qkv16    = (f16*)(ws + 213909504);                  // 616,562,688
  f16*   attn16   = (f16*)(ws + 830472192);                  // 205,520,896
  float* bias_all = (float*)(ws + 1035993088);               //     262,144

  cvt_kernel<<<2048, 256, 0, stream>>>(x, x16, 102760448 / 4);
  cvt_kernel<<<1024, 256, 0, stream>>>(qkv_w, wq16, 3145728 / 4);
  cvt_kernel<<<512, 256, 0, stream>>>(proj_w, wp16, 1048576 / 4);
  bias_kernel<<<16, 64, 0, stream>>>(rpb, bias_all);

  // qkv = x @ qkv_w^T + qkv_b   [100352][3072] fp16   (392 x 12 tiles)
  gemm256<f16><<<4704, 512, 0, stream>>>(x16, wq16, qkv_b, qkv16, 3072, 12);
  // attention per (window, head)
  attn_kernel<<<2048 * 16, 64, 0, stream>>>(qkv16, bias_all, attn16);
  // out = attn @ proj_w^T + proj_b   [100352][1024] fp32  (392 x 4 tiles)
  gemm256<float><<<1568, 512, 0, stream>>>(attn16, wp16, proj_b, out, 1024, 4);
}

// Round 6
// 1475.459 us; speedup vs baseline: 1.0682x; 1.0682x over previous
//
#include <hip/hip_runtime.h>

// MHSA with relative position bias (Swin window attention), MI355X gfx950.
// B=2048 windows, N=49 tokens, C=1024, 16 heads x 64. fp16 MFMA, fp32 accum.
// Round 6: GEMM = R2's measured-good addressing (zero LDS conflicts, 64B-coalesced
// staging, 16x16x32 MFMA) + R3's read-ahead pipeline:
//   phase = one 32-col K-half: {12 ds_read_b128 for half p+1 | stage half p+4}
//   -> 32 independent MFMAs on half p's frags -> lgkm(0), vmcnt(8), barrier.
//   4-slot LDS rotation (4x16KB A + 4x16KB B = 128 KiB), frag regs double-buffered.

typedef _Float16 f16;
typedef _Float16 f16x8 __attribute__((ext_vector_type(8)));
typedef _Float16 f16x4 __attribute__((ext_vector_type(4)));
typedef float f32x4 __attribute__((ext_vector_type(4)));

#define G1P(p) ((const __attribute__((address_space(1))) unsigned int*)(p))
#define L3P(p) ((__attribute__((address_space(3))) unsigned int*)(p))

static const size_t MROW_MAX = 100351;   // clamp for padded rows 49..63 (attn)

// ---------------- fp32 -> fp16 convert (vec4) ----------------
__global__ void cvt_kernel(const float* __restrict__ in, f16* __restrict__ out, int n4) {
  int i = blockIdx.x * blockDim.x + threadIdx.x;
  int stride = gridDim.x * blockDim.x;
  const float4* in4 = (const float4*)in;
  f16x4* out4 = (f16x4*)out;
  for (; i < n4; i += stride) {
    float4 v = in4[i];
    f16x4 o = { (f16)v.x, (f16)v.y, (f16)v.z, (f16)v.w };
    out4[i] = o;
  }
}

// ---------------- bias table: bias_all[h][64][64], mask folded in ----------------
__global__ void bias_kernel(const float* __restrict__ rpb, float* __restrict__ bias_all) {
  int h = blockIdx.x;
  for (int e = threadIdx.x; e < 4096; e += blockDim.x) {
    int n = e >> 6, m = e & 63;
    float v = -1e30f;
    if (n < 49 && m < 49) {
      int in_ = n / 7, jn = n % 7, im = m / 7, jm = m % 7;
      v = rpb[h * 169 + (im - in_ + 6) * 13 + (jm - jn + 6)];
    }
    bias_all[h * 4096 + e] = v;
  }
}

// ---------------- 256x256 pipelined GEMM: C[M,N] = A[M,K=1024] @ B[N,K]^T + bias ----
#define WVM(N) asm volatile("s_waitcnt vmcnt(" #N ")" ::: "memory")
#define WLG    asm volatile("s_waitcnt lgkmcnt(0)" ::: "memory")
#define SB     __builtin_amdgcn_s_barrier()
#define SCB    __builtin_amdgcn_sched_barrier(0)
#define MF16(a, b, c) __builtin_amdgcn_mfma_f32_16x16x32_f16(a, b, c, 0, 0, 0)

// stage one K-half pair (A 16KB + B 16KB); per wave 2 A + 2 B dest KB-blocks.
// Panel layout [256 rows][32 f16]; 16B chunk phys = logical ^ ((row>>1)&3),
// applied on the GLOBAL source (sce) -> linear LDS dest, coalesced 64B/quad.
#define STG(CE, SLOT)                                                                       \
  {                                                                                         \
    const f16* ga_ = Ap + arow_g + (CE);                                                    \
    __builtin_amdgcn_global_load_lds(G1P(ga_), L3P(lds + (SLOT) * 16384 + wid * 2048), 16, 0, 0); \
    __builtin_amdgcn_global_load_lds(G1P(ga_ + 16 * 1024), L3P(lds + (SLOT) * 16384 + wid * 2048 + 1024), 16, 0, 0); \
    const f16* gb_ = Bp + brow_g + (CE);                                                    \
    __builtin_amdgcn_global_load_lds(G1P(gb_), L3P(lds + 65536 + (SLOT) * 16384 + wid * 2048), 16, 0, 0); \
    __builtin_amdgcn_global_load_lds(G1P(gb_ + 16 * 1024), L3P(lds + 65536 + (SLOT) * 16384 + wid * 2048 + 1024), 16, 0, 0); \
  }

// frag reads for one K-half: 8 A (16 rows x 4 lanes each, swizzled chunk) + 4 B
#define READS(AF, BF, RSLOT)                                                                \
  {                                                                                         \
    const char* ab_ = lds + (RSLOT) * 16384 + arowb;                                        \
    _Pragma("unroll") for (int t_ = 0; t_ < 8; ++t_) AF[t_] = *(const f16x8*)(ab_ + t_ * 1024); \
    const char* bb_ = lds + 65536 + (RSLOT) * 16384 + browb;                                \
    _Pragma("unroll") for (int u_ = 0; u_ < 4; ++u_) BF[u_] = *(const f16x8*)(bb_ + u_ * 1024); \
  }

// 32 independent MFMAs (each acc element written once per phase)
#define MFMAS(AF, BF)                                                                       \
  {                                                                                         \
    __builtin_amdgcn_s_setprio(1);                                                          \
    _Pragma("unroll") for (int u_ = 0; u_ < 4; ++u_)                                        \
      _Pragma("unroll") for (int t_ = 0; t_ < 8; ++t_)                                      \
        acc[t_][u_] = MF16(AF[t_], BF[u_], acc[t_][u_]);                                    \
    __builtin_amdgcn_s_setprio(0);                                                          \
  }

template <typename OutT>
__global__ __launch_bounds__(512, 2)
void gemm256(const f16* __restrict__ Ap, const f16* __restrict__ Bp,
             const float* __restrict__ bias, OutT* __restrict__ C,
             int N, int ntiles_n) {
  __shared__ char lds[131072];  // A slots 0..3 at 0; B slots 0..3 at 65536
  const int tid = threadIdx.x;
  const int wid = tid >> 6, ln = tid & 63;
  const int l15 = ln & 15, lhi = ln >> 4;
  const int wm = wid >> 2, wn = wid & 3;
  // read-side lane constants (R2 pattern, measured 0 conflicts)
  const int swz = ((lhi ^ ((l15 >> 1) & 3)) << 4);
  const int arowb = (wm * 128 + l15) * 64 + swz;   // + t*1024 per 16-row frag
  const int browb = (wn * 64 + l15) * 64 + swz;    // + u*1024
  // staging-side lane constants (64B-coalesced per quad, swizzle on source)
  const int srow = ln >> 2;
  const int sce = (((ln & 3) ^ ((ln >> 3) & 3)) << 3);

  // XCD-chunked 1D swizzle (grid divisible by 8), n-fastest for A-panel L2 reuse
  const int nblk = gridDim.x;
  const int wg = (blockIdx.x & 7) * (nblk >> 3) + (blockIdx.x >> 3);
  const int bn = wg % ntiles_n, bm = wg / ntiles_n;
  const int m0 = bm * 256, n0 = bn * 256;

  const size_t arow_g = (size_t)(m0 + wid * 32 + srow) * 1024 + sce;
  const size_t brow_g = (size_t)(n0 + wid * 32 + srow) * 1024 + sce;

  f32x4 acc[8][4];
#pragma unroll
  for (int i = 0; i < 8; ++i)
#pragma unroll
    for (int j = 0; j < 4; ++j) acc[i][j] = (f32x4){0.f, 0.f, 0.f, 0.f};
  f16x8 af0[8], af1[8], bf0[4], bf1[4];

  // prologue: stage halves 0..3 into slots 0..3; read frags of half 0
  STG(0, 0); STG(32, 1); STG(64, 2); STG(96, 3);
  WVM(8);            // halves 0,1 landed
  SB; SCB;
  READS(af0, bf0, 0);
  WLG;
  SB; SCB;

  // main loop: phases 0..27 (compute half p; read half p+1; stage half p+4)
  int ce = 128;      // element column of next staged half
  for (int i = 0; i < 7; ++i) {
    READS(af1, bf1, 1); STG(ce, 0);       SCB; MFMAS(af0, bf0); WLG; WVM(8); SB; SCB;
    READS(af0, bf0, 2); STG(ce + 32, 1);  SCB; MFMAS(af1, bf1); WLG; WVM(8); SB; SCB;
    READS(af1, bf1, 3); STG(ce + 64, 2);  SCB; MFMAS(af0, bf0); WLG; WVM(8); SB; SCB;
    READS(af0, bf0, 0); STG(ce + 96, 3);  SCB; MFMAS(af1, bf1); WLG; WVM(8); SB; SCB;
    ce += 128;
  }
  // drain: phases 28..31
  READS(af1, bf1, 1); SCB; MFMAS(af0, bf0); WLG; WVM(4); SB; SCB;
  READS(af0, bf0, 2); SCB; MFMAS(af1, bf1); WLG; WVM(0); SB; SCB;
  READS(af1, bf1, 3); SCB; MFMAS(af0, bf0); WLG; SB; SCB;
  MFMAS(af1, bf1);

  // epilogue: C row = t*16 + lhi*4 + r, col = u*16 + l15 (m89-verified layout)
  float bv[4];
#pragma unroll
  for (int u = 0; u < 4; ++u) bv[u] = bias[n0 + wn * 64 + u * 16 + l15];
#pragma unroll
  for (int t = 0; t < 8; ++t)
#pragma unroll
    for (int u = 0; u < 4; ++u)
#pragma unroll
      for (int r = 0; r < 4; ++r) {
        int grow = m0 + wm * 128 + t * 16 + lhi * 4 + r;
        int gcol = n0 + wn * 64 + u * 16 + l15;
        C[(size_t)grow * N + gcol] = (OutT)(acc[t][u][r] + bv[u]);
      }
}

// ---------------- attention: one wave per (window, head) ----------------
__global__ __launch_bounds__(64)
void attn_kernel(const f16* __restrict__ qkv,        // [MTOT][3072] q|k|v
                 const float* __restrict__ bias_all, // [16][64][64]
                 f16* __restrict__ out) {             // [MTOT][1024]
  __shared__ char lds[24576];  // K:[0,8K)  Vt:[8K,16K)  P:[16K,24K)
  const int bh = blockIdx.x;
  const int b = bh >> 4, h = bh & 15;
  const int ln = threadIdx.x;
  const int l15 = ln & 15, lhi = ln >> 4;
  const size_t base = (size_t)b * 49;

  f16x8 qf[4][2];
#pragma unroll
  for (int t = 0; t < 4; ++t) {
    size_t row = base + t * 16 + l15;
    if (row > MROW_MAX) row = MROW_MAX;
    const f16* qp = qkv + row * 3072 + h * 64 + lhi * 8;
    qf[t][0] = *(const f16x8*)(qp);
    qf[t][1] = *(const f16x8*)(qp + 32);
  }
  {
    int rA = ln >> 3, lc = ln & 7;
#pragma unroll
    for (int c = 0; c < 8; ++c) {
      int r = c * 8 + rA;
      int ce = (lc ^ (r & 7)) << 3;
      size_t row = base + r;
      if (row > MROW_MAX) row = MROW_MAX;
      const f16* g = qkv + row * 3072 + 1024 + h * 64 + ce;
      __builtin_amdgcn_global_load_lds(G1P(g), L3P(lds + c * 1024), 16, 0, 0);
    }
  }
  {
    size_t row = base + ln;
    if (row > MROW_MAX) row = MROW_MAX;
    const f16* vp = qkv + row * 3072 + 2048 + h * 64;
    f16x8 vr[8];
#pragma unroll
    for (int j = 0; j < 8; ++j) vr[j] = *(const f16x8*)(vp + j * 8);
#pragma unroll
    for (int d = 0; d < 64; ++d)
      *(f16*)(lds + 8192 + d * 128 + ((ln * 2) ^ ((d & 7) << 4))) = vr[d >> 3][d & 7];
  }
  __syncthreads();

  f32x4 acc[4][4];
#pragma unroll
  for (int i = 0; i < 4; ++i)
#pragma unroll
    for (int j = 0; j < 4; ++j) acc[i][j] = (f32x4){0.f, 0.f, 0.f, 0.f};
#pragma unroll
  for (int kk = 0; kk < 2; ++kk) {
    f16x8 bf[4];
#pragma unroll
    for (int t = 0; t < 4; ++t) {
      int mr = t * 16 + l15;
      int pb = (kk * 64 + lhi * 16) ^ ((mr & 7) << 4);
      bf[t] = *(const f16x8*)(lds + mr * 128 + pb);
    }
#pragma unroll
    for (int i = 0; i < 4; ++i)
#pragma unroll
      for (int j = 0; j < 4; ++j)
        acc[i][j] = __builtin_amdgcn_mfma_f32_16x16x32_f16(qf[i][kk], bf[j], acc[i][j], 0, 0, 0);
  }

  const float* bb = bias_all + h * 4096;
#pragma unroll
  for (int i = 0; i < 4; ++i) {
#pragma unroll
    for (int r = 0; r < 4; ++r) {
      int n = i * 16 + lhi * 4 + r;
      float lv[4];
#pragma unroll
      for (int j = 0; j < 4; ++j)
        lv[j] = acc[i][j][r] * 0.125f + bb[n * 64 + j * 16 + l15];
      float Mx = fmaxf(fmaxf(lv[0], lv[1]), fmaxf(lv[2], lv[3]));
#pragma unroll
      for (int off = 1; off < 16; off <<= 1) Mx = fmaxf(Mx, __shfl_xor(Mx, off));
      float s = 0.f;
#pragma unroll
      for (int j = 0; j < 4; ++j) { lv[j] = __expf(lv[j] - Mx); s += lv[j]; }
#pragma unroll
      for (int off = 1; off < 16; off <<= 1) s += __shfl_xor(s, off);
      float inv = 1.f / s;
#pragma unroll
      for (int j = 0; j < 4; ++j) {
        int m = j * 16 + l15;
        *(f16*)(lds + 16384 + n * 128 + ((m * 2) ^ ((n & 7) << 4))) = (f16)(lv[j] * inv);
      }
    }
  }
  __syncthreads();

  f32x4 o[4][4];
#pragma unroll
  for (int i = 0; i < 4; ++i)
#pragma unroll
    for (int j = 0; j < 4; ++j) o[i][j] = (f32x4){0.f, 0.f, 0.f, 0.f};
#pragma unroll
  for (int kk = 0; kk < 2; ++kk) {
    f16x8 af[4], bf[4];
#pragma unroll
    for (int t = 0; t < 4; ++t) {
      int nr = t * 16 + l15;
      int pb = (kk * 64 + lhi * 16) ^ ((nr & 7) << 4);
      af[t] = *(const f16x8*)(lds + 16384 + nr * 128 + pb);
      bf[t] = *(const f16x8*)(lds + 8192 + nr * 128 + pb);
    }
#pragma unroll
    for (int i = 0; i < 4; ++i)
#pragma unroll
      for (int j = 0; j < 4; ++j)
        o[i][j] = __builtin_amdgcn_mfma_f32_16x16x32_f16(af[i], bf[j], o[i][j], 0, 0, 0);
  }
#pragma unroll
  for (int i = 0; i < 4; ++i)
#pragma unroll
    for (int j = 0; j < 4; ++j)
#pragma unroll
      for (int r = 0; r < 4; ++r) {
        int n = i * 16 + lhi * 4 + r;
        if (n < 49)
          out[(base + n) * 1024 + h * 64 + j * 16 + l15] = (f16)o[i][j][r];
      }
}

extern "C" void kernel_launch(void* const* d_in, const int* in_sizes, int n_in,
                              void* d_out, int out_size, void* d_ws, size_t ws_size,
                              hipStream_t stream) {
  const float* x      = (const float*)d_in[0];  // [100352][1024]
  const float* qkv_w  = (const float*)d_in[1];  // [3072][1024]
  const float* qkv_b  = (const float*)d_in[2];  // [3072]
  const float* rpb    = (const float*)d_in[3];  // [16][13][13]
  const float* proj_w = (const float*)d_in[4];  // [1024][1024]
  const float* proj_b = (const float*)d_in[5];  // [1024]
  float* out = (float*)d_out;

  char* ws = (char*)d_ws;
  f16*   x16      = (f16*)(ws);                              // 205,520,896
  f16*   wq16     = (f16*)(ws + 205520896);                  //   6,291,456
  f16*   wp16     = (f16*)(ws + 211812352);                  //   2,097,152
  f16*   qkv16    = (f16*)(ws + 213909504);                  // 616,562,688
  f16*   attn16   = (f16*)(ws + 830472192);                  // 205,520,896
  float* bias_all = (float*)(ws + 1035993088);               //     262,144

  cvt_kernel<<<2048, 256, 0, stream>>>(x, x16, 102760448 / 4);
  cvt_kernel<<<1024, 256, 0, stream>>>(qkv_w, wq16, 3145728 / 4);
  cvt_kernel<<<512, 256, 0, stream>>>(proj_w, wp16, 1048576 / 4);
  bias_kernel<<<16, 64, 0, stream>>>(rpb, bias_all);

  // qkv = x @ qkv_w^T + qkv_b   [100352][3072] fp16   (392 x 12 tiles)
  gemm256<f16><<<4704, 512, 0, stream>>>(x16, wq16, qkv_b, qkv16, 3072, 12);
  // attention per (window, head)
  attn_kernel<<<2048 * 16, 64, 0, stream>>>(qkv16, bias_all, attn16);
  // out = attn @ proj_w^T + proj_b   [100352][1024] fp32  (392 x 4 tiles)
  gemm256<float><<<1568, 512, 0, stream>>>(attn16, wp16, proj_b, out, 1024, 4);
}

// Round 7
// 1334.525 us; speedup vs baseline: 1.1810x; 1.1056x over previous
//
#include <hip/hip_runtime.h>

// MHSA with relative position bias (Swin window attention), MI355X gfx950.
// B=2048 windows, N=49 tokens, C=1024, 16 heads x 64. fp16 MFMA, fp32 accum.
// Round 7: GEMM reverted to the Round-2 8-phase 256x256 schedule (best measured:
// 694 us, MfmaUtil 44, 0 bank conflicts; R3-R6 pipelined variants all regressed).
// Attention: P-matrix now reuses K's LDS buffer (K dead after QK^T) ->
// LDS 24KB -> 16KB -> occupancy 6 -> 10 blocks/CU (+67% latency hiding).

typedef _Float16 f16;
typedef _Float16 f16x8 __attribute__((ext_vector_type(8)));
typedef _Float16 f16x4 __attribute__((ext_vector_type(4)));
typedef float f32x4 __attribute__((ext_vector_type(4)));

#define G1P(p) ((const __attribute__((address_space(1))) unsigned int*)(p))
#define L3P(p) ((__attribute__((address_space(3))) unsigned int*)(p))

static const size_t MROW_MAX = 100351;   // clamp for padded rows 49..63 (attn)

// ---------------- fp32 -> fp16 convert (vec4) ----------------
__global__ void cvt_kernel(const float* __restrict__ in, f16* __restrict__ out, int n4) {
  int i = blockIdx.x * blockDim.x + threadIdx.x;
  int stride = gridDim.x * blockDim.x;
  const float4* in4 = (const float4*)in;
  f16x4* out4 = (f16x4*)out;
  for (; i < n4; i += stride) {
    float4 v = in4[i];
    f16x4 o = { (f16)v.x, (f16)v.y, (f16)v.z, (f16)v.w };
    out4[i] = o;
  }
}

// ---------------- bias table: bias_all[h][64][64], mask folded in ----------------
__global__ void bias_kernel(const float* __restrict__ rpb, float* __restrict__ bias_all) {
  int h = blockIdx.x;
  for (int e = threadIdx.x; e < 4096; e += blockDim.x) {
    int n = e >> 6, m = e & 63;
    float v = -1e30f;
    if (n < 49 && m < 49) {
      int in_ = n / 7, jn = n % 7, im = m / 7, jm = m % 7;
      v = rpb[h * 169 + (im - in_ + 6) * 13 + (jm - jn + 6)];
    }
    bias_all[h * 4096 + e] = v;
  }
}

// ---------------- 256x256 8-phase GEMM: C[M,N] = A[M,K] @ B[N,K]^T + bias ----------------
// (Round-2 verbatim: best measured schedule.)
// LDS per buffer (64KB): A[kk0] 0 / A[kk1] 16384 / B[kk0] 32768 / B[kk1] 49152.
// Buffer 1 at +65536. Panel layout [256 rows][32 f16]; 16B chunk swizzled by
// chunk_phys = chunk_log ^ ((row>>1)&3), applied on the GLOBAL source (write side)
// and on the ds_read address (read side) -- both reduce to lane constants.

#define VM4 asm volatile("s_waitcnt vmcnt(4)" ::: "memory")
#define VM0 asm volatile("s_waitcnt vmcnt(0)" ::: "memory")
#define NOVM ((void)0)
#define NOSTG ((void)0)

// one half-tile (16KB = 16 slots of 1KB): per wave 2 slots (wid*2, wid*2+1)
#define STAGE(GB, ROW0, COL0, LDSOFF)                                              \
  {                                                                                \
    const f16* s0_ = (GB) + (size_t)((ROW0) + wid * 32 + srow) * K + ((COL0) + sce); \
    __builtin_amdgcn_global_load_lds(G1P(s0_), L3P(lds + (LDSOFF) + wid * 2048), 16, 0, 0); \
    const f16* s1_ = s0_ + (size_t)16 * K;                                         \
    __builtin_amdgcn_global_load_lds(G1P(s1_), L3P(lds + (LDSOFF) + wid * 2048 + 1024), 16, 0, 0); \
  }

#define MFMA4(AREG, ROW)                                                           \
  acc[ROW][0] = __builtin_amdgcn_mfma_f32_16x16x32_f16(AREG, b0, acc[ROW][0], 0, 0, 0); \
  acc[ROW][1] = __builtin_amdgcn_mfma_f32_16x16x32_f16(AREG, b1, acc[ROW][1], 0, 0, 0); \
  acc[ROW][2] = __builtin_amdgcn_mfma_f32_16x16x32_f16(AREG, b2, acc[ROW][2], 0, 0, 0); \
  acc[ROW][3] = __builtin_amdgcn_mfma_f32_16x16x32_f16(AREG, b3, acc[ROW][3], 0, 0, 0);

#define PHASE(ABASE, BBASE, MH, STG, VMW)                                          \
  {                                                                                \
    f16x8 a0 = *(const f16x8*)((ABASE) + (wm * 128 + (MH) * 64 +  0 + l15) * 64 + swz); \
    f16x8 a1 = *(const f16x8*)((ABASE) + (wm * 128 + (MH) * 64 + 16 + l15) * 64 + swz); \
    f16x8 a2 = *(const f16x8*)((ABASE) + (wm * 128 + (MH) * 64 + 32 + l15) * 64 + swz); \
    f16x8 a3 = *(const f16x8*)((ABASE) + (wm * 128 + (MH) * 64 + 48 + l15) * 64 + swz); \
    if ((MH) == 0) {                                                               \
      b0 = *(const f16x8*)((BBASE) + (wn * 64 +  0 + l15) * 64 + swz);             \
      b1 = *(const f16x8*)((BBASE) + (wn * 64 + 16 + l15) * 64 + swz);             \
      b2 = *(const f16x8*)((BBASE) + (wn * 64 + 32 + l15) * 64 + swz);             \
      b3 = *(const f16x8*)((BBASE) + (wn * 64 + 48 + l15) * 64 + swz);             \
    }                                                                              \
    STG;                                                                           \
    __builtin_amdgcn_s_barrier();                                                  \
    asm volatile("s_waitcnt lgkmcnt(0)" ::: "memory");                             \
    __builtin_amdgcn_sched_barrier(0);                                             \
    __builtin_amdgcn_s_setprio(1);                                                 \
    MFMA4(a0, (MH) * 4 + 0) MFMA4(a1, (MH) * 4 + 1)                                \
    MFMA4(a2, (MH) * 4 + 2) MFMA4(a3, (MH) * 4 + 3)                                \
    __builtin_amdgcn_s_setprio(0);                                                 \
    VMW;                                                                           \
    __builtin_amdgcn_s_barrier();                                                  \
  }

template <typename OutT>
__global__ __launch_bounds__(512, 2)
void gemm256(const f16* __restrict__ A, const f16* __restrict__ B,
             const float* __restrict__ bias, OutT* __restrict__ C,
             int N, int K, int ntiles_n) {
  __shared__ char lds[131072];
  const int tid = threadIdx.x;
  const int wid = tid >> 6, ln = tid & 63;
  const int l15 = ln & 15, lhi = ln >> 4;
  const int wm = wid >> 2, wn = wid & 3;
  // lane constants: staging source chunk swizzle and fragment-read chunk swizzle
  const int srow = ln >> 2;                              // row within 16-row slot
  const int sce = (((ln & 3) ^ ((ln >> 3) & 3)) << 3);   // source element offset (swizzled)
  const int swz = ((lhi ^ ((l15 >> 1) & 3)) << 4);       // read byte-chunk offset (swizzled)

  // XCD-chunked 1D swizzle (grid divisible by 8), n-fastest for A-panel L2 reuse
  const int nblk = gridDim.x;
  const int wg = (blockIdx.x & 7) * (nblk >> 3) + (blockIdx.x >> 3);
  const int bn = wg % ntiles_n, bm = wg / ntiles_n;
  const int m0 = bm * 256, n0 = bn * 256;

  f32x4 acc[8][4];
#pragma unroll
  for (int i = 0; i < 8; ++i)
#pragma unroll
    for (int j = 0; j < 4; ++j) acc[i][j] = (f32x4){0.f, 0.f, 0.f, 0.f};
  f16x8 b0, b1, b2, b3;

  // prologue: tile0 (4 halves) + tile1 kk0 halves; keep last 2 halves in flight
  STAGE(A, m0, 0, 0);                 // Ak0(0) -> buf0
  STAGE(B, n0, 0, 32768);             // Bk0(0)
  STAGE(A, m0, 32, 16384);            // Ak1(0)
  STAGE(B, n0, 32, 49152);            // Bk1(0)
  STAGE(A, m0, 64, 65536);            // Ak0(1) -> buf1
  STAGE(B, n0, 64, 98304);            // Bk0(1)
  VM4;
  __builtin_amdgcn_s_barrier();

  // main: 7 iterations x 2 K-tiles (tiles 0..13); K = 1024 = 16 tiles of 64
  for (int i = 0; i < 7; ++i) {
    const int cT1k1 = (2 * i + 1) * 64 + 32;
    const int cT2k0 = (2 * i + 2) * 64;
    const int cT2k1 = cT2k0 + 32;
    const int cT3k0 = (2 * i + 3) * 64;
    // tile 2i (buf0)
    PHASE(lds + 0,      lds + 32768,  0, STAGE(A, m0, cT1k1, 81920),  NOVM);
    PHASE(lds + 0,      lds + 32768,  1, STAGE(B, n0, cT1k1, 114688), NOVM);
    PHASE(lds + 16384,  lds + 49152,  0, STAGE(A, m0, cT2k0, 0),      NOVM);
    PHASE(lds + 16384,  lds + 49152,  1, STAGE(B, n0, cT2k0, 32768),  VM4);
    // tile 2i+1 (buf1)
    PHASE(lds + 65536,  lds + 98304,  0, STAGE(A, m0, cT2k1, 16384),  NOVM);
    PHASE(lds + 65536,  lds + 98304,  1, STAGE(B, n0, cT2k1, 49152),  NOVM);
    PHASE(lds + 81920,  lds + 114688, 0, STAGE(A, m0, cT3k0, 65536),  NOVM);
    PHASE(lds + 81920,  lds + 114688, 1, STAGE(B, n0, cT3k0, 98304),  VM4);
  }
  // tail: tile 14 (buf0) -- stage only tile 15 kk1 halves, then drain
  PHASE(lds + 0,      lds + 32768,  0, STAGE(A, m0, 15 * 64 + 32, 81920),  NOVM);
  PHASE(lds + 0,      lds + 32768,  1, STAGE(B, n0, 15 * 64 + 32, 114688), NOVM);
  PHASE(lds + 16384,  lds + 49152,  0, NOSTG, NOVM);
  PHASE(lds + 16384,  lds + 49152,  1, NOSTG, VM0);
  // tile 15 (buf1)
  PHASE(lds + 65536,  lds + 98304,  0, NOSTG, NOVM);
  PHASE(lds + 65536,  lds + 98304,  1, NOSTG, NOVM);
  PHASE(lds + 81920,  lds + 114688, 0, NOSTG, NOVM);
  PHASE(lds + 81920,  lds + 114688, 1, NOSTG, NOVM);

  // epilogue
  float bv[4];
#pragma unroll
  for (int j = 0; j < 4; ++j) bv[j] = bias[n0 + wn * 64 + j * 16 + l15];
#pragma unroll
  for (int ii = 0; ii < 8; ++ii)
#pragma unroll
    for (int j = 0; j < 4; ++j)
#pragma unroll
      for (int r = 0; r < 4; ++r) {
        int gr = m0 + wm * 128 + ii * 16 + lhi * 4 + r;
        int gc = n0 + wn * 64 + j * 16 + l15;
        C[(size_t)gr * N + gc] = (OutT)(acc[ii][j][r] + bv[j]);
      }
}

// ---------------- attention: one wave per (window, head) ----------------
// LDS 16KB: K/P share [0,8K) (K dead after QK^T; same-wave DS ops are in-order);
// Vt at [8K,16K). 16KB/block -> 10 blocks/CU occupancy (was 6 at 24KB).
__global__ __launch_bounds__(64)
void attn_kernel(const f16* __restrict__ qkv,        // [MTOT][3072] q|k|v
                 const float* __restrict__ bias_all, // [16][64][64]
                 f16* __restrict__ out) {             // [MTOT][1024]
  __shared__ char lds[16384];  // K then P:[0,8K)  Vt:[8K,16K)
  const int bh = blockIdx.x;
  const int b = bh >> 4, h = bh & 15;
  const int ln = threadIdx.x;
  const int l15 = ln & 15, lhi = ln >> 4;
  const size_t base = (size_t)b * 49;

  f16x8 qf[4][2];
#pragma unroll
  for (int t = 0; t < 4; ++t) {
    size_t row = base + t * 16 + l15;
    if (row > MROW_MAX) row = MROW_MAX;
    const f16* qp = qkv + row * 3072 + h * 64 + lhi * 8;
    qf[t][0] = *(const f16x8*)(qp);
    qf[t][1] = *(const f16x8*)(qp + 32);
  }
  {
    int rA = ln >> 3, lc = ln & 7;
#pragma unroll
    for (int c = 0; c < 8; ++c) {
      int r = c * 8 + rA;
      int ce = (lc ^ (r & 7)) << 3;
      size_t row = base + r;
      if (row > MROW_MAX) row = MROW_MAX;
      const f16* g = qkv + row * 3072 + 1024 + h * 64 + ce;
      __builtin_amdgcn_global_load_lds(G1P(g), L3P(lds + c * 1024), 16, 0, 0);
    }
  }
  {
    size_t row = base + ln;
    if (row > MROW_MAX) row = MROW_MAX;
    const f16* vp = qkv + row * 3072 + 2048 + h * 64;
    f16x8 vr[8];
#pragma unroll
    for (int j = 0; j < 8; ++j) vr[j] = *(const f16x8*)(vp + j * 8);
#pragma unroll
    for (int d = 0; d < 64; ++d)
      *(f16*)(lds + 8192 + d * 128 + ((ln * 2) ^ ((d & 7) << 4))) = vr[d >> 3][d & 7];
  }
  __syncthreads();

  // S = Q @ K^T
  f32x4 acc[4][4];
#pragma unroll
  for (int i = 0; i < 4; ++i)
#pragma unroll
    for (int j = 0; j < 4; ++j) acc[i][j] = (f32x4){0.f, 0.f, 0.f, 0.f};
#pragma unroll
  for (int kk = 0; kk < 2; ++kk) {
    f16x8 bf[4];
#pragma unroll
    for (int t = 0; t < 4; ++t) {
      int mr = t * 16 + l15;
      int pb = (kk * 64 + lhi * 16) ^ ((mr & 7) << 4);
      bf[t] = *(const f16x8*)(lds + mr * 128 + pb);
    }
#pragma unroll
    for (int i = 0; i < 4; ++i)
#pragma unroll
      for (int j = 0; j < 4; ++j)
        acc[i][j] = __builtin_amdgcn_mfma_f32_16x16x32_f16(qf[i][kk], bf[j], acc[i][j], 0, 0, 0);
  }

  // softmax; P overwrites K's buffer (K fully consumed into acc)
  const float* bb = bias_all + h * 4096;
#pragma unroll
  for (int i = 0; i < 4; ++i) {
#pragma unroll
    for (int r = 0; r < 4; ++r) {
      int n = i * 16 + lhi * 4 + r;
      float lv[4];
#pragma unroll
      for (int j = 0; j < 4; ++j)
        lv[j] = acc[i][j][r] * 0.125f + bb[n * 64 + j * 16 + l15];
      float Mx = fmaxf(fmaxf(lv[0], lv[1]), fmaxf(lv[2], lv[3]));
#pragma unroll
      for (int off = 1; off < 16; off <<= 1) Mx = fmaxf(Mx, __shfl_xor(Mx, off));
      float s = 0.f;
#pragma unroll
      for (int j = 0; j < 4; ++j) { lv[j] = __expf(lv[j] - Mx); s += lv[j]; }
#pragma unroll
      for (int off = 1; off < 16; off <<= 1) s += __shfl_xor(s, off);
      float inv = 1.f / s;
#pragma unroll
      for (int j = 0; j < 4; ++j) {
        int m = j * 16 + l15;
        *(f16*)(lds + n * 128 + ((m * 2) ^ ((n & 7) << 4))) = (f16)(lv[j] * inv);
      }
    }
  }
  __syncthreads();

  // O = P @ V
  f32x4 o[4][4];
#pragma unroll
  for (int i = 0; i < 4; ++i)
#pragma unroll
    for (int j = 0; j < 4; ++j) o[i][j] = (f32x4){0.f, 0.f, 0.f, 0.f};
#pragma unroll
  for (int kk = 0; kk < 2; ++kk) {
    f16x8 af[4], bf[4];
#pragma unroll
    for (int t = 0; t < 4; ++t) {
      int nr = t * 16 + l15;
      int pb = (kk * 64 + lhi * 16) ^ ((nr & 7) << 4);
      af[t] = *(const f16x8*)(lds + nr * 128 + pb);
      bf[t] = *(const f16x8*)(lds + 8192 + nr * 128 + pb);
    }
#pragma unroll
    for (int i = 0; i < 4; ++i)
#pragma unroll
      for (int j = 0; j < 4; ++j)
        o[i][j] = __builtin_amdgcn_mfma_f32_16x16x32_f16(af[i], bf[j], o[i][j], 0, 0, 0);
  }
#pragma unroll
  for (int i = 0; i < 4; ++i)
#pragma unroll
    for (int j = 0; j < 4; ++j)
#pragma unroll
      for (int r = 0; r < 4; ++r) {
        int n = i * 16 + lhi * 4 + r;
        if (n < 49)
          out[(base + n) * 1024 + h * 64 + j * 16 + l15] = (f16)o[i][j][r];
      }
}

extern "C" void kernel_launch(void* const* d_in, const int* in_sizes, int n_in,
                              void* d_out, int out_size, void* d_ws, size_t ws_size,
                              hipStream_t stream) {
  const float* x      = (const float*)d_in[0];  // [100352][1024]
  const float* qkv_w  = (const float*)d_in[1];  // [3072][1024]
  const float* qkv_b  = (const float*)d_in[2];  // [3072]
  const float* rpb    = (const float*)d_in[3];  // [16][13][13]
  const float* proj_w = (const float*)d_in[4];  // [1024][1024]
  const float* proj_b = (const float*)d_in[5];  // [1024]
  float* out = (float*)d_out;

  char* ws = (char*)d_ws;
  f16*   x16      = (f16*)(ws);                              // 205,520,896
  f16*   wq16     = (f16*)(ws + 205520896);                  //   6,291,456
  f16*   wp16     = (f16*)(ws + 211812352);                  //   2,097,152
  f16*   qkv16    = (f16*)(ws + 213909504);                  // 616,562,688
  f16*   attn16   = (f16*)(ws + 830472192);                  // 205,520,896
  float* bias_all = (float*)(ws + 1035993088);               //     262,144

  cvt_kernel<<<2048, 256, 0, stream>>>(x, x16, 102760448 / 4);
  cvt_kernel<<<1024, 256, 0, stream>>>(qkv_w, wq16, 3145728 / 4);
  cvt_kernel<<<512, 256, 0, stream>>>(proj_w, wp16, 1048576 / 4);
  bias_kernel<<<16, 64, 0, stream>>>(rpb, bias_all);

  // qkv = x @ qkv_w^T + qkv_b   [100352][3072] fp16   (392 x 12 tiles)
  gemm256<f16><<<4704, 512, 0, stream>>>(x16, wq16, qkv_b, qkv16, 3072, 1024, 12);
  // attention per (window, head)
  attn_kernel<<<2048 * 16, 64, 0, stream>>>(qkv16, bias_all, attn16);
  // out = attn @ proj_w^T + proj_b   [100352][1024] fp32  (392 x 4 tiles)
  gemm256<float><<<1568, 512, 0, stream>>>(attn16, wp16, proj_b, out, 1024, 1024, 4);
}